// Round 5
// baseline (439.915 us; speedup 1.0000x reference)
//
#include <hip/hip_runtime.h>
#include <hip/hip_bf16.h>
#include <math.h>

// S,B,H,NH = 2048,4,1024,16; HD=64
constexpr int S_ = 2048, B_ = 4, H_ = 1024, NH_ = 16, HD_ = 64;

typedef __attribute__((ext_vector_type(8))) short short8;   // 8 bf16 (4 VGPRs)
typedef __attribute__((ext_vector_type(4))) short short4v;  // 4 bf16
typedef __attribute__((ext_vector_type(4))) float floatx4;  // MFMA C/D
typedef __attribute__((ext_vector_type(2))) unsigned uint2v;

static __device__ __forceinline__ short f2bf(float f) {
    union { float f; unsigned u; } v; v.f = f;
    unsigned r = v.u + 0x7FFFu + ((v.u >> 16) & 1u);  // RNE
    return (short)(r >> 16);
}

// pack two f32 -> one u32 of two bf16 (truncation), via v_perm_b32
static __device__ __forceinline__ unsigned pack_bf(float p0, float p1) {
    return __builtin_amdgcn_perm(__float_as_uint(p1), __float_as_uint(p0), 0x07060302u);
}
static __device__ __forceinline__ float bfl(unsigned u) { return __uint_as_float(u << 16); }
static __device__ __forceinline__ float bfh(unsigned u) { return __uint_as_float(u & 0xFFFF0000u); }

// async global->LDS, 16B per lane; LDS dest = wave-uniform base + lane*16
static __device__ __forceinline__ void gl2lds16(const void* g, void* l) {
    __builtin_amdgcn_global_load_lds(
        (const __attribute__((address_space(1))) void*)g,
        (__attribute__((address_space(3))) void*)l, 16, 0, 0);
}

// P-fragment redistribution (in-register, replaces Ps LDS round-trip).
static __device__ __forceinline__ short8 pswz(unsigned a0, unsigned a1,
                                              unsigned b0, unsigned b1) {
    uint2v r0 = __builtin_amdgcn_permlane32_swap(a0, b0, false, false);
    uint2v s0 = __builtin_amdgcn_permlane16_swap(r0.x, r0.y, false, false);
    uint2v r1 = __builtin_amdgcn_permlane32_swap(a1, b1, false, false);
    uint2v s1 = __builtin_amdgcn_permlane16_swap(r1.x, r1.y, false, false);
    union { unsigned u[4]; short8 s; } o;
    o.u[0] = s0.x;  // W0: t = dq*8 + {0,1}
    o.u[1] = s1.x;  // W1: t = dq*8 + {2,3}
    o.u[2] = s0.y;  // W2: t = dq*8 + {4,5}
    o.u[3] = s1.y;  // W3: t = dq*8 + {6,7}
    return o.s;
}

// ---------------------------------------------------------------------------
// fused fp32 -> bf16 convert for hidden / Wqkv / Wd
// ---------------------------------------------------------------------------
__global__ __launch_bounds__(256) void cvt3_kernel(
    const float* __restrict__ a, short* __restrict__ oa, int na,
    const float* __restrict__ b, short* __restrict__ ob, int nb,
    const float* __restrict__ c, short* __restrict__ oc, int nc)
{
    const int idx = blockIdx.x * 256 + threadIdx.x;
    const float* src; short* dst; int i;
    if (idx < na)            { src = a; dst = oa; i = idx; }
    else if (idx < na + nb)  { src = b; dst = ob; i = idx - na; }
    else                     { src = c; dst = oc; i = idx - na - nb; }
    const float4 v = ((const float4*)src)[i];
    short4v o = { (short)f2bf(v.x), (short)f2bf(v.y), (short)f2bf(v.z), (short)f2bf(v.w) };
    ((short4v*)dst)[i] = o;
}

// ---------------------------------------------------------------------------
// mask int32 -> keep-bytes (0xFF = keep, 0x00 = masked). 4 ints -> 1 dword.
// ---------------------------------------------------------------------------
__global__ __launch_bounds__(256) void mask_u8_kernel(
    const int* __restrict__ m, unsigned* __restrict__ mb)
{
    const int i = blockIdx.x * 256 + threadIdx.x;
    const int4 v = ((const int4*)m)[i];
    unsigned r = (v.x ? 0u : 0xFFu)      | (v.y ? 0u : 0xFF00u) |
                 (v.z ? 0u : 0xFF0000u)  | (v.w ? 0u : 0xFF000000u);
    mb[i] = r;
}

// ---------------------------------------------------------------------------
// QKV GEMM, bf16 MFMA, swizzled LDS. Epilogue: Qb/Kb/Vb all [bh][s][d]
// (coalesced); Q pre-scaled by (1/sqrt(HD)) * log2(e) so flash uses raw exp2.
// ---------------------------------------------------------------------------
__global__ __launch_bounds__(256) void gemm_qkv_mfma(
    const short* __restrict__ A, const short* __restrict__ Bw,
    const float* __restrict__ bias,
    short* __restrict__ Qb, short* __restrict__ Kb, short* __restrict__ Vb)
{
    constexpr int K = H_;  // 1024
    __shared__ __align__(16) short As[128 * 64];
    __shared__ __align__(16) short Bs[128 * 64];

    const int t = threadIdx.x;
    const int wave = t >> 6, lane = t & 63;
    const int l15 = lane & 15, quad = lane >> 4;
    const int wm = wave & 1, wn = wave >> 1;
    const int row0 = blockIdx.y * 128;
    const int col0 = blockIdx.x * 128;

    floatx4 acc[4][4];
#pragma unroll
    for (int mi = 0; mi < 4; ++mi)
#pragma unroll
        for (int ni = 0; ni < 4; ++ni)
            acc[mi][ni] = (floatx4){0.f, 0.f, 0.f, 0.f};

    for (int k0 = 0; k0 < K; k0 += 64) {
        // stage with XOR chunk swizzle: LDS slot (r, jp) holds global chunk jp^(r&7)
#pragma unroll
        for (int j = 0; j < 4; ++j) {
            const int c = wave * 256 + j * 64 + lane;
            const int r = c >> 3, jg = ((c & 7) ^ (r & 7)) * 8;
            gl2lds16(A  + (size_t)(row0 + r) * K + k0 + jg, &As[(wave * 256 + j * 64) * 8]);
            gl2lds16(Bw + (size_t)(col0 + r) * K + k0 + jg, &Bs[(wave * 256 + j * 64) * 8]);
        }
        __syncthreads();
#pragma unroll
        for (int kk = 0; kk < 64; kk += 32) {
            short8 af[4], bfr[4];
#pragma unroll
            for (int mi = 0; mi < 4; ++mi) {
                const int R = wm * 64 + mi * 16 + l15;
                af[mi] = *(const short8*)&As[R * 64 + ((((kk >> 3) + quad) ^ (R & 7)) * 8)];
            }
#pragma unroll
            for (int ni = 0; ni < 4; ++ni) {
                const int R = wn * 64 + ni * 16 + l15;
                bfr[ni] = *(const short8*)&Bs[R * 64 + ((((kk >> 3) + quad) ^ (R & 7)) * 8)];
            }
#pragma unroll
            for (int mi = 0; mi < 4; ++mi)
#pragma unroll
                for (int ni = 0; ni < 4; ++ni)
                    acc[mi][ni] = __builtin_amdgcn_mfma_f32_16x16x32_bf16(
                        af[mi], bfr[ni], acc[mi][ni], 0, 0, 0);
        }
        __syncthreads();
    }

#pragma unroll
    for (int ni = 0; ni < 4; ++ni) {
        const int gc = col0 + wn * 64 + ni * 16 + l15;
        const float bv = bias[gc];
        const int hh = gc / 192;
        const int rem = gc - hh * 192;
        const int which = rem >> 6, d = rem & 63;
#pragma unroll
        for (int mi = 0; mi < 4; ++mi)
#pragma unroll
            for (int i = 0; i < 4; ++i) {
                const int gr = row0 + wm * 64 + mi * 16 + quad * 4 + i;
                const int s = gr >> 2, bb = gr & 3;      // row = s*B + b
                float fv = acc[mi][ni][i] + bv;
                const size_t ho = (size_t)(bb * NH_ + hh);
                // 0.125 * log2(e): scores arrive pre-multiplied for exp2
                if (which == 0)      Qb[(ho * S_ + s) * HD_ + d] = f2bf(fv * 0.1803368801111204f);
                else if (which == 1) Kb[(ho * S_ + s) * HD_ + d] = f2bf(fv);
                else                 Vb[(ho * S_ + s) * HD_ + d] = f2bf(fv);
            }
    }
}

// ---------------------------------------------------------------------------
// V transpose: Vb [bh][s][d] -> Vtb [bh][d][s], 64x64 tiles via swizzled LDS.
// ---------------------------------------------------------------------------
__global__ __launch_bounds__(256) void vtrans_kernel(
    const short* __restrict__ Vb, short* __restrict__ Vtb)
{
    const int bh = blockIdx.y;
    const int s0 = blockIdx.x * 64;
    __shared__ __align__(16) short T[64 * 64];
    const int t = threadIdx.x;

#pragma unroll
    for (int it = 0; it < 2; ++it) {
        const int c = t + it * 256;
        const int r = c >> 3, jp = c & 7;
        const int jg = jp ^ ((r >> 3) & 7);
        *(short8*)&T[r * 64 + jp * 8] =
            *(const short8*)(Vb + ((size_t)bh * S_ + s0 + r) * HD_ + jg * 8);
    }
    __syncthreads();

#pragma unroll
    for (int it = 0; it < 2; ++it) {
        const int c = t + it * 256;
        const int d = c >> 3, sg = (c & 7) * 8;
        short8 v;
#pragma unroll
        for (int k = 0; k < 8; ++k) {
            const int r = sg + k;
            v[k] = T[r * 64 + (((d >> 3) ^ ((r >> 3) & 7)) * 8) + (d & 7)];
        }
        *(short8*)(Vtb + ((size_t)bh * HD_ + d) * S_ + s0 + sg) = v;
    }
}

// ---------------------------------------------------------------------------
// Dense GEMM, bf16 MFMA, swizzled LDS: out = ctxb @ Wd^T + bd (fp32 out)
// ---------------------------------------------------------------------------
__global__ __launch_bounds__(256) void gemm_dense_mfma(
    const short* __restrict__ A, const short* __restrict__ Bw,
    const float* __restrict__ bias, float* __restrict__ out)
{
    constexpr int K = H_;  // 1024
    __shared__ __align__(16) short As[128 * 64];
    __shared__ __align__(16) short Bs[128 * 64];

    const int t = threadIdx.x;
    const int wave = t >> 6, lane = t & 63;
    const int l15 = lane & 15, quad = lane >> 4;
    const int wm = wave & 1, wn = wave >> 1;
    const int row0 = blockIdx.y * 128;
    const int col0 = blockIdx.x * 128;

    floatx4 acc[4][4];
#pragma unroll
    for (int mi = 0; mi < 4; ++mi)
#pragma unroll
        for (int ni = 0; ni < 4; ++ni)
            acc[mi][ni] = (floatx4){0.f, 0.f, 0.f, 0.f};

    for (int k0 = 0; k0 < K; k0 += 64) {
#pragma unroll
        for (int j = 0; j < 4; ++j) {
            const int c = wave * 256 + j * 64 + lane;
            const int r = c >> 3, jg = ((c & 7) ^ (r & 7)) * 8;
            gl2lds16(A  + (size_t)(row0 + r) * K + k0 + jg, &As[(wave * 256 + j * 64) * 8]);
            gl2lds16(Bw + (size_t)(col0 + r) * K + k0 + jg, &Bs[(wave * 256 + j * 64) * 8]);
        }
        __syncthreads();
#pragma unroll
        for (int kk = 0; kk < 64; kk += 32) {
            short8 af[4], bfr[4];
#pragma unroll
            for (int mi = 0; mi < 4; ++mi) {
                const int R = wm * 64 + mi * 16 + l15;
                af[mi] = *(const short8*)&As[R * 64 + ((((kk >> 3) + quad) ^ (R & 7)) * 8)];
            }
#pragma unroll
            for (int ni = 0; ni < 4; ++ni) {
                const int R = wn * 64 + ni * 16 + l15;
                bfr[ni] = *(const short8*)&Bs[R * 64 + ((((kk >> 3) + quad) ^ (R & 7)) * 8)];
            }
#pragma unroll
            for (int mi = 0; mi < 4; ++mi)
#pragma unroll
                for (int ni = 0; ni < 4; ++ni)
                    acc[mi][ni] = __builtin_amdgcn_mfma_f32_16x16x32_bf16(
                        af[mi], bfr[ni], acc[mi][ni], 0, 0, 0);
        }
        __syncthreads();
    }

#pragma unroll
    for (int ni = 0; ni < 4; ++ni) {
        const int gc = col0 + wn * 64 + ni * 16 + l15;
        const float bv = bias[gc];
#pragma unroll
        for (int mi = 0; mi < 4; ++mi)
#pragma unroll
            for (int i = 0; i < 4; ++i) {
                const int gr = row0 + wm * 64 + mi * 16 + quad * 4 + i;
                out[(size_t)gr * H_ + gc] = acc[mi][ni][i] + bv;
            }
    }
}

// ---------------------------------------------------------------------------
// Flash attention v5, MFMA bf16.
//   R4 post-mortem: warm-cache replay still 165us -> NOT BW-bound; the
//   mu<-mun register copy forced an implicit vmcnt(0) drain every tile
//   (mask loads are the youngest VMEM ops), defeating the counted-vmcnt
//   pipeline. v5:
//   * NO cross-iteration register copies: 2-phase unrolled mask sets
//     (even bodies use muA / prefetch muB, odd bodies swap; tile 31 peeled).
//     Implicit wait before mask use is vmcnt(12) -> stage(k+2) stays in
//     flight across tiles. vmcnt never drains to 0 mid-loop, for real.
//   * QBLK=128 (2 q-groups/wave, VGPR ~110) + 3 x 16KB LDS buffers = 48 KB
//     -> 3 blocks/CU = 12 waves/CU: TLP and pipeline stack.
//   * Ledger: body k top outstanding = stage(k+1)[4]+mask(k)[8] -> explicit
//     vmcnt(12) retires stage(k). Each wave stages its own LDS quarter, so
//     own-vmcnt + s_barrier gives cross-wave visibility (8-phase argument).
//   * setprio(1) around MFMA clusters; sched_barrier(0) pins issue blocks.
// ---------------------------------------------------------------------------
__global__ __launch_bounds__(256, 3) void flash_mfma_kernel(
    const short* __restrict__ Qb, const short* __restrict__ Kb,
    const short* __restrict__ Vtb, const unsigned char* __restrict__ mask8,
    short* __restrict__ ctxb)
{
    const int bh = blockIdx.y;
    const int b  = bh >> 4;          // / NH_
    const int h  = bh & 15;          // % NH_
    const int s0 = blockIdx.x * 128;

    const int tdx  = threadIdx.x;
    const int wave = tdx >> 6;
    const int lane = tdx & 63;
    const int l15  = lane & 15;
    const int quad = lane >> 4;

    __shared__ __align__(16) short Ks [3 * 4096];   // [buf][key][d], chunk-swizzled
    __shared__ __align__(16) short Vts[3 * 4096];   // [buf][d][key], chunk-swizzled

    // Q fragments: wave owns q rows [s0+wave*32, +32), 2 groups of 16
    const short* Qg = Qb + ((size_t)bh * S_ + s0 + wave * 32 + l15) * HD_;
    short8 qf[2][2];
#pragma unroll
    for (int g = 0; g < 2; ++g) {
        qf[g][0] = *(const short8*)(Qg + g * 16 * HD_ + quad * 8);
        qf[g][1] = *(const short8*)(Qg + g * 16 * HD_ + 32 + quad * 8);
    }

    const short* Kbase  = Kb  + (size_t)bh * S_ * HD_;
    const short* Vtbase = Vtb + (size_t)bh * HD_ * S_;
    const unsigned char* mr = mask8 + ((size_t)b * S_ + s0 + wave * 32 + l15) * S_ + quad * 4;

    floatx4 o[2][4];
    float ls[2] = {0.f, 0.f};
#pragma unroll
    for (int g = 0; g < 2; ++g)
#pragma unroll
        for (int n0 = 0; n0 < 4; ++n0) o[g][n0] = (floatx4){0.f, 0.f, 0.f, 0.f};

    // staging chunk geometry (per lane, loop-invariant)
    const int cb0 = wave * 64, cb1 = (4 + wave) * 64;
    const int c0 = cb0 + lane,  c1 = cb1 + lane;
    const int r0 = c0 >> 3, jg0 = ((c0 & 7) ^ (r0 & 7)) * 8;
    const int r1 = c1 >> 3, jg1 = ((c1 & 7) ^ (r1 & 7)) * 8;

    unsigned muA[2][4], muB[2][4];

    // prologue (FIFO order: stage0 | stage1 | mask0->muA)
    gl2lds16(Kbase  + (size_t)r0 * HD_ + jg0, &Ks[cb0 * 8]);
    gl2lds16(Kbase  + (size_t)r1 * HD_ + jg1, &Ks[cb1 * 8]);
    gl2lds16(Vtbase + (size_t)r0 * S_ + jg0,  &Vts[cb0 * 8]);
    gl2lds16(Vtbase + (size_t)r1 * S_ + jg1,  &Vts[cb1 * 8]);
    __builtin_amdgcn_sched_barrier(0);
    gl2lds16(Kbase  + (size_t)(64 + r0) * HD_ + jg0, &Ks[4096 + cb0 * 8]);
    gl2lds16(Kbase  + (size_t)(64 + r1) * HD_ + jg1, &Ks[4096 + cb1 * 8]);
    gl2lds16(Vtbase + (size_t)r0 * S_ + 64 + jg0,    &Vts[4096 + cb0 * 8]);
    gl2lds16(Vtbase + (size_t)r1 * S_ + 64 + jg1,    &Vts[4096 + cb1 * 8]);
    __builtin_amdgcn_sched_barrier(0);
#pragma unroll
    for (int g = 0; g < 2; ++g)
#pragma unroll
        for (int n0 = 0; n0 < 4; ++n0)
            muA[g][n0] = *(const unsigned*)(mr + (size_t)g * 16 * S_ + n0 * 16);

    const floatx4 z4 = {0.f, 0.f, 0.f, 0.f};
    int boC = 0, boS = 2 * 4096;

    // compute one tile from buf boC using mask regs mc; updates o, ls.
    auto compute_tile = [&](const unsigned (&mc)[2][4]) {
        floatx4 sc[2][4];
        __builtin_amdgcn_s_setprio(1);
#pragma unroll
        for (int n0 = 0; n0 < 4; ++n0) {
            const int R = n0 * 16 + l15, xr = R & 7;
            const short8 kb0 = *(const short8*)&Ks[boC + R * 64 + ((quad ^ xr) * 8)];
            const short8 kb1 = *(const short8*)&Ks[boC + R * 64 + (((quad + 4) ^ xr) * 8)];
            sc[0][n0] = __builtin_amdgcn_mfma_f32_16x16x32_bf16(kb0, qf[0][0], z4, 0, 0, 0);
            sc[0][n0] = __builtin_amdgcn_mfma_f32_16x16x32_bf16(kb1, qf[0][1], sc[0][n0], 0, 0, 0);
            sc[1][n0] = __builtin_amdgcn_mfma_f32_16x16x32_bf16(kb0, qf[1][0], z4, 0, 0, 0);
            sc[1][n0] = __builtin_amdgcn_mfma_f32_16x16x32_bf16(kb1, qf[1][1], sc[1][n0], 0, 0, 0);
        }
        __builtin_amdgcn_s_setprio(0);
        unsigned uu[2][4][2];
#pragma unroll
        for (int g = 0; g < 2; ++g)
#pragma unroll
            for (int n0 = 0; n0 < 4; ++n0) {
                const floatx4 v = sc[g][n0];
                const unsigned q0 = __builtin_amdgcn_perm(0u, mc[g][n0], 0x01010000u);
                const unsigned q1 = __builtin_amdgcn_perm(0u, mc[g][n0], 0x03030202u);
                const unsigned u0 = pack_bf(__builtin_amdgcn_exp2f(v[0]),
                                            __builtin_amdgcn_exp2f(v[1])) & q0;
                const unsigned u1 = pack_bf(__builtin_amdgcn_exp2f(v[2]),
                                            __builtin_amdgcn_exp2f(v[3])) & q1;
                ls[g] += (bfl(u0) + bfh(u0)) + (bfl(u1) + bfh(u1));
                uu[g][n0][0] = u0; uu[g][n0][1] = u1;
            }
        short8 pa[2][2];
        pa[0][0] = pswz(uu[0][0][0], uu[0][0][1], uu[0][1][0], uu[0][1][1]);
        pa[0][1] = pswz(uu[0][2][0], uu[0][2][1], uu[0][3][0], uu[0][3][1]);
        pa[1][0] = pswz(uu[1][0][0], uu[1][0][1], uu[1][1][0], uu[1][1][1]);
        pa[1][1] = pswz(uu[1][2][0], uu[1][2][1], uu[1][3][0], uu[1][3][1]);
        __builtin_amdgcn_s_setprio(1);
#pragma unroll
        for (int n0 = 0; n0 < 4; ++n0) {
            const int R = n0 * 16 + l15, xr = R & 7;
            const short8 vb0 = *(const short8*)&Vts[boC + R * 64 + ((quad ^ xr) * 8)];
            const short8 vb1 = *(const short8*)&Vts[boC + R * 64 + (((quad + 4) ^ xr) * 8)];
            o[0][n0] = __builtin_amdgcn_mfma_f32_16x16x32_bf16(pa[0][0], vb0, o[0][n0], 0, 0, 0);
            o[0][n0] = __builtin_amdgcn_mfma_f32_16x16x32_bf16(pa[0][1], vb1, o[0][n0], 0, 0, 0);
            o[1][n0] = __builtin_amdgcn_mfma_f32_16x16x32_bf16(pa[1][0], vb0, o[1][n0], 0, 0, 0);
            o[1][n0] = __builtin_amdgcn_mfma_f32_16x16x32_bf16(pa[1][1], vb1, o[1][n0], 0, 0, 0);
        }
        __builtin_amdgcn_s_setprio(0);
    };

    // one pipeline body: wait stage(it), barrier, stage(it+2), mask(it+1)->mn,
    // compute(mc), rotate buffers. No register copies anywhere.
    auto body = [&](int it, const unsigned (&mc)[2][4], unsigned (&mn)[2][4]) {
        asm volatile("s_waitcnt vmcnt(12)" ::: "memory");
        __builtin_amdgcn_s_barrier();
        __builtin_amdgcn_sched_barrier(0);
        if (it < 30) {
            const size_t tn = (size_t)(it + 2) * 64;
            gl2lds16(Kbase  + (tn + r0) * HD_ + jg0,      &Ks[boS + cb0 * 8]);
            gl2lds16(Kbase  + (tn + r1) * HD_ + jg1,      &Ks[boS + cb1 * 8]);
            gl2lds16(Vtbase + (size_t)r0 * S_ + tn + jg0, &Vts[boS + cb0 * 8]);
            gl2lds16(Vtbase + (size_t)r1 * S_ + tn + jg1, &Vts[boS + cb1 * 8]);
        }
        __builtin_amdgcn_sched_barrier(0);
        {
            const int tn1 = (it + 1) * 64;
#pragma unroll
            for (int g = 0; g < 2; ++g)
#pragma unroll
                for (int n0 = 0; n0 < 4; ++n0)
                    mn[g][n0] = *(const unsigned*)(mr + (size_t)g * 16 * S_ + tn1 + n0 * 16);
        }
        __builtin_amdgcn_sched_barrier(0);
        compute_tile(mc);
        boC = (boC == 2 * 4096) ? 0 : boC + 4096;
        boS = (boS == 2 * 4096) ? 0 : boS + 4096;
    };

#pragma unroll 1
    for (int it = 0; it < 30; it += 2) {
        body(it,     muA, muB);
        body(it + 1, muB, muA);
    }
    body(30, muA, muB);   // stages nothing (it>=30), loads mask(31)->muB
    // final tile 31: outstanding = mask(31)[8]; stage(31) already retired.
    asm volatile("s_waitcnt vmcnt(8)" ::: "memory");
    __builtin_amdgcn_s_barrier();
    __builtin_amdgcn_sched_barrier(0);
    compute_tile(muB);

    // --- epilogue: l reduce over quads, normalize, store ---
#pragma unroll
    for (int g = 0; g < 2; ++g) {
        float lg = ls[g];
        lg += __shfl_xor(lg, 16);
        lg += __shfl_xor(lg, 32);
        const float li = 1.f / lg;
#pragma unroll
        for (int i = 0; i < 4; ++i) {
            const float la = __shfl(li, quad * 4 + i);
            const int sA = s0 + wave * 32 + g * 16 + quad * 4 + i;
#pragma unroll
            for (int n0 = 0; n0 < 4; ++n0)
                ctxb[((size_t)sA * B_ + b) * H_ + h * HD_ + n0 * 16 + l15] =
                    f2bf(o[g][n0][i] * la);
        }
    }
}

// ---------------------------------------------------------------------------
extern "C" void kernel_launch(void* const* d_in, const int* in_sizes, int n_in,
                              void* d_out, int out_size, void* d_ws, size_t ws_size,
                              hipStream_t stream)
{
    const float* hidden = (const float*)d_in[0];
    const int*   mask   = (const int*)d_in[1];
    const float* Wqkv   = (const float*)d_in[2];
    const float* bqkv   = (const float*)d_in[3];
    const float* Wd     = (const float*)d_in[4];
    const float* bd     = (const float*)d_in[5];
    float* out = (float*)d_out;

    const size_t HE = (size_t)B_ * NH_ * S_ * HD_;   // 8388608
    short* hBF    = (short*)d_ws;
    short* WqkvBF = hBF + (size_t)S_ * B_ * H_;
    short* WdBF   = WqkvBF + (size_t)3 * H_ * H_;
    short* Qb     = WdBF + (size_t)H_ * H_;
    short* Kb     = Qb + HE;
    short* Vb     = Kb + HE;
    short* Vtb    = Vb + HE;
    short* ctxb   = Vtb + HE;
    // mask keep-bytes: B*S*S bytes == S*B*H*2 bytes -> alias hBF, which is
    // dead after gemm_qkv (mask_u8 launched after it, stream-ordered).
    unsigned char* mask8 = (unsigned char*)hBF;

    const int nh4 = (S_ * B_ * H_) / 4;   // 2097152
    const int nw4 = (3 * H_ * H_) / 4;    // 786432
    const int nd4 = (H_ * H_) / 4;        // 262144
    hipLaunchKernelGGL(cvt3_kernel, dim3((nh4 + nw4 + nd4) / 256), dim3(256), 0, stream,
                       hidden, hBF, nh4, Wqkv, WqkvBF, nw4, Wd, WdBF, nd4);

    hipLaunchKernelGGL(gemm_qkv_mfma, dim3((3 * H_) / 128, (S_ * B_) / 128), dim3(256), 0, stream,
                       hBF, WqkvBF, bqkv, Qb, Kb, Vb);
    hipLaunchKernelGGL(mask_u8_kernel, dim3((B_ * S_ * S_ / 4) / 256), dim3(256), 0, stream,
                       mask, (unsigned*)mask8);
    hipLaunchKernelGGL(vtrans_kernel, dim3(S_ / 64, B_ * NH_), dim3(256), 0, stream,
                       Vb, Vtb);
    hipLaunchKernelGGL(flash_mfma_kernel, dim3(S_ / 128, B_ * NH_), dim3(256), 0, stream,
                       Qb, Kb, Vtb, mask8, ctxb);
    hipLaunchKernelGGL(gemm_dense_mfma, dim3(H_ / 128, (S_ * B_) / 128), dim3(256), 0, stream,
                       ctxb, WdBF, bd, out);
}

// Round 6
// 363.592 us; speedup vs baseline: 1.2099x; 1.2099x over previous
//
#include <hip/hip_runtime.h>
#include <hip/hip_bf16.h>
#include <math.h>

// S,B,H,NH = 2048,4,1024,16; HD=64
constexpr int S_ = 2048, B_ = 4, H_ = 1024, NH_ = 16, HD_ = 64;

typedef __attribute__((ext_vector_type(8))) short short8;   // 8 bf16 (4 VGPRs)
typedef __attribute__((ext_vector_type(4))) short short4v;  // 4 bf16
typedef __attribute__((ext_vector_type(4))) float floatx4;  // MFMA C/D
typedef __attribute__((ext_vector_type(2))) unsigned uint2v;

static __device__ __forceinline__ short f2bf(float f) {
    union { float f; unsigned u; } v; v.f = f;
    unsigned r = v.u + 0x7FFFu + ((v.u >> 16) & 1u);  // RNE
    return (short)(r >> 16);
}

// pack two f32 -> one u32 of two bf16 (truncation), via v_perm_b32
static __device__ __forceinline__ unsigned pack_bf(float p0, float p1) {
    return __builtin_amdgcn_perm(__float_as_uint(p1), __float_as_uint(p0), 0x07060302u);
}
static __device__ __forceinline__ float bfl(unsigned u) { return __uint_as_float(u << 16); }
static __device__ __forceinline__ float bfh(unsigned u) { return __uint_as_float(u & 0xFFFF0000u); }

// async global->LDS, 16B per lane; LDS dest = wave-uniform base + lane*16
static __device__ __forceinline__ void gl2lds16(const void* g, void* l) {
    __builtin_amdgcn_global_load_lds(
        (const __attribute__((address_space(1))) void*)g,
        (__attribute__((address_space(3))) void*)l, 16, 0, 0);
}

// P-fragment redistribution (in-register, replaces Ps LDS round-trip).
static __device__ __forceinline__ short8 pswz(unsigned a0, unsigned a1,
                                              unsigned b0, unsigned b1) {
    uint2v r0 = __builtin_amdgcn_permlane32_swap(a0, b0, false, false);
    uint2v s0 = __builtin_amdgcn_permlane16_swap(r0.x, r0.y, false, false);
    uint2v r1 = __builtin_amdgcn_permlane32_swap(a1, b1, false, false);
    uint2v s1 = __builtin_amdgcn_permlane16_swap(r1.x, r1.y, false, false);
    union { unsigned u[4]; short8 s; } o;
    o.u[0] = s0.x;  // W0: t = dq*8 + {0,1}
    o.u[1] = s1.x;  // W1: t = dq*8 + {2,3}
    o.u[2] = s0.y;  // W2: t = dq*8 + {4,5}
    o.u[3] = s1.y;  // W3: t = dq*8 + {6,7}
    return o.s;
}

// ---------------------------------------------------------------------------
// fused fp32 -> bf16 convert for hidden / Wqkv / Wd
// ---------------------------------------------------------------------------
__global__ __launch_bounds__(256) void cvt3_kernel(
    const float* __restrict__ a, short* __restrict__ oa, int na,
    const float* __restrict__ b, short* __restrict__ ob, int nb,
    const float* __restrict__ c, short* __restrict__ oc, int nc)
{
    const int idx = blockIdx.x * 256 + threadIdx.x;
    const float* src; short* dst; int i;
    if (idx < na)            { src = a; dst = oa; i = idx; }
    else if (idx < na + nb)  { src = b; dst = ob; i = idx - na; }
    else                     { src = c; dst = oc; i = idx - na - nb; }
    const float4 v = ((const float4*)src)[i];
    short4v o = { (short)f2bf(v.x), (short)f2bf(v.y), (short)f2bf(v.z), (short)f2bf(v.w) };
    ((short4v*)dst)[i] = o;
}

// ---------------------------------------------------------------------------
// mask int32 -> keep-bytes (0xFF = keep, 0x00 = masked). 4 ints -> 1 dword.
// ---------------------------------------------------------------------------
__global__ __launch_bounds__(256) void mask_u8_kernel(
    const int* __restrict__ m, unsigned* __restrict__ mb)
{
    const int i = blockIdx.x * 256 + threadIdx.x;
    const int4 v = ((const int4*)m)[i];
    unsigned r = (v.x ? 0u : 0xFFu)      | (v.y ? 0u : 0xFF00u) |
                 (v.z ? 0u : 0xFF0000u)  | (v.w ? 0u : 0xFF000000u);
    mb[i] = r;
}

// ---------------------------------------------------------------------------
// QKV GEMM, bf16 MFMA, swizzled LDS. Epilogue: Qb/Kb/Vb all [bh][s][d]
// (coalesced); Q pre-scaled by (1/sqrt(HD)) * log2(e) so flash uses raw exp2.
// ---------------------------------------------------------------------------
__global__ __launch_bounds__(256) void gemm_qkv_mfma(
    const short* __restrict__ A, const short* __restrict__ Bw,
    const float* __restrict__ bias,
    short* __restrict__ Qb, short* __restrict__ Kb, short* __restrict__ Vb)
{
    constexpr int K = H_;  // 1024
    __shared__ __align__(16) short As[128 * 64];
    __shared__ __align__(16) short Bs[128 * 64];

    const int t = threadIdx.x;
    const int wave = t >> 6, lane = t & 63;
    const int l15 = lane & 15, quad = lane >> 4;
    const int wm = wave & 1, wn = wave >> 1;
    const int row0 = blockIdx.y * 128;
    const int col0 = blockIdx.x * 128;

    floatx4 acc[4][4];
#pragma unroll
    for (int mi = 0; mi < 4; ++mi)
#pragma unroll
        for (int ni = 0; ni < 4; ++ni)
            acc[mi][ni] = (floatx4){0.f, 0.f, 0.f, 0.f};

    for (int k0 = 0; k0 < K; k0 += 64) {
        // stage with XOR chunk swizzle: LDS slot (r, jp) holds global chunk jp^(r&7)
#pragma unroll
        for (int j = 0; j < 4; ++j) {
            const int c = wave * 256 + j * 64 + lane;
            const int r = c >> 3, jg = ((c & 7) ^ (r & 7)) * 8;
            gl2lds16(A  + (size_t)(row0 + r) * K + k0 + jg, &As[(wave * 256 + j * 64) * 8]);
            gl2lds16(Bw + (size_t)(col0 + r) * K + k0 + jg, &Bs[(wave * 256 + j * 64) * 8]);
        }
        __syncthreads();
#pragma unroll
        for (int kk = 0; kk < 64; kk += 32) {
            short8 af[4], bfr[4];
#pragma unroll
            for (int mi = 0; mi < 4; ++mi) {
                const int R = wm * 64 + mi * 16 + l15;
                af[mi] = *(const short8*)&As[R * 64 + ((((kk >> 3) + quad) ^ (R & 7)) * 8)];
            }
#pragma unroll
            for (int ni = 0; ni < 4; ++ni) {
                const int R = wn * 64 + ni * 16 + l15;
                bfr[ni] = *(const short8*)&Bs[R * 64 + ((((kk >> 3) + quad) ^ (R & 7)) * 8)];
            }
#pragma unroll
            for (int mi = 0; mi < 4; ++mi)
#pragma unroll
                for (int ni = 0; ni < 4; ++ni)
                    acc[mi][ni] = __builtin_amdgcn_mfma_f32_16x16x32_bf16(
                        af[mi], bfr[ni], acc[mi][ni], 0, 0, 0);
        }
        __syncthreads();
    }

#pragma unroll
    for (int ni = 0; ni < 4; ++ni) {
        const int gc = col0 + wn * 64 + ni * 16 + l15;
        const float bv = bias[gc];
        const int hh = gc / 192;
        const int rem = gc - hh * 192;
        const int which = rem >> 6, d = rem & 63;
#pragma unroll
        for (int mi = 0; mi < 4; ++mi)
#pragma unroll
            for (int i = 0; i < 4; ++i) {
                const int gr = row0 + wm * 64 + mi * 16 + quad * 4 + i;
                const int s = gr >> 2, bb = gr & 3;      // row = s*B + b
                float fv = acc[mi][ni][i] + bv;
                const size_t ho = (size_t)(bb * NH_ + hh);
                // 0.125 * log2(e): scores arrive pre-multiplied for exp2
                if (which == 0)      Qb[(ho * S_ + s) * HD_ + d] = f2bf(fv * 0.1803368801111204f);
                else if (which == 1) Kb[(ho * S_ + s) * HD_ + d] = f2bf(fv);
                else                 Vb[(ho * S_ + s) * HD_ + d] = f2bf(fv);
            }
    }
}

// ---------------------------------------------------------------------------
// V transpose: Vb [bh][s][d] -> Vtb [bh][d][s], 64x64 tiles via swizzled LDS.
// ---------------------------------------------------------------------------
__global__ __launch_bounds__(256) void vtrans_kernel(
    const short* __restrict__ Vb, short* __restrict__ Vtb)
{
    const int bh = blockIdx.y;
    const int s0 = blockIdx.x * 64;
    __shared__ __align__(16) short T[64 * 64];
    const int t = threadIdx.x;

#pragma unroll
    for (int it = 0; it < 2; ++it) {
        const int c = t + it * 256;
        const int r = c >> 3, jp = c & 7;
        const int jg = jp ^ ((r >> 3) & 7);
        *(short8*)&T[r * 64 + jp * 8] =
            *(const short8*)(Vb + ((size_t)bh * S_ + s0 + r) * HD_ + jg * 8);
    }
    __syncthreads();

#pragma unroll
    for (int it = 0; it < 2; ++it) {
        const int c = t + it * 256;
        const int d = c >> 3, sg = (c & 7) * 8;
        short8 v;
#pragma unroll
        for (int k = 0; k < 8; ++k) {
            const int r = sg + k;
            v[k] = T[r * 64 + (((d >> 3) ^ ((r >> 3) & 7)) * 8) + (d & 7)];
        }
        *(short8*)(Vtb + ((size_t)bh * HD_ + d) * S_ + s0 + sg) = v;
    }
}

// ---------------------------------------------------------------------------
// Dense GEMM, bf16 MFMA, swizzled LDS: out = ctxb @ Wd^T + bd (fp32 out)
// ---------------------------------------------------------------------------
__global__ __launch_bounds__(256) void gemm_dense_mfma(
    const short* __restrict__ A, const short* __restrict__ Bw,
    const float* __restrict__ bias, float* __restrict__ out)
{
    constexpr int K = H_;  // 1024
    __shared__ __align__(16) short As[128 * 64];
    __shared__ __align__(16) short Bs[128 * 64];

    const int t = threadIdx.x;
    const int wave = t >> 6, lane = t & 63;
    const int l15 = lane & 15, quad = lane >> 4;
    const int wm = wave & 1, wn = wave >> 1;
    const int row0 = blockIdx.y * 128;
    const int col0 = blockIdx.x * 128;

    floatx4 acc[4][4];
#pragma unroll
    for (int mi = 0; mi < 4; ++mi)
#pragma unroll
        for (int ni = 0; ni < 4; ++ni)
            acc[mi][ni] = (floatx4){0.f, 0.f, 0.f, 0.f};

    for (int k0 = 0; k0 < K; k0 += 64) {
#pragma unroll
        for (int j = 0; j < 4; ++j) {
            const int c = wave * 256 + j * 64 + lane;
            const int r = c >> 3, jg = ((c & 7) ^ (r & 7)) * 8;
            gl2lds16(A  + (size_t)(row0 + r) * K + k0 + jg, &As[(wave * 256 + j * 64) * 8]);
            gl2lds16(Bw + (size_t)(col0 + r) * K + k0 + jg, &Bs[(wave * 256 + j * 64) * 8]);
        }
        __syncthreads();
#pragma unroll
        for (int kk = 0; kk < 64; kk += 32) {
            short8 af[4], bfr[4];
#pragma unroll
            for (int mi = 0; mi < 4; ++mi) {
                const int R = wm * 64 + mi * 16 + l15;
                af[mi] = *(const short8*)&As[R * 64 + ((((kk >> 3) + quad) ^ (R & 7)) * 8)];
            }
#pragma unroll
            for (int ni = 0; ni < 4; ++ni) {
                const int R = wn * 64 + ni * 16 + l15;
                bfr[ni] = *(const short8*)&Bs[R * 64 + ((((kk >> 3) + quad) ^ (R & 7)) * 8)];
            }
#pragma unroll
            for (int mi = 0; mi < 4; ++mi)
#pragma unroll
                for (int ni = 0; ni < 4; ++ni)
                    acc[mi][ni] = __builtin_amdgcn_mfma_f32_16x16x32_bf16(
                        af[mi], bfr[ni], acc[mi][ni], 0, 0, 0);
        }
        __syncthreads();
    }

#pragma unroll
    for (int ni = 0; ni < 4; ++ni) {
        const int gc = col0 + wn * 64 + ni * 16 + l15;
        const float bv = bias[gc];
#pragma unroll
        for (int mi = 0; mi < 4; ++mi)
#pragma unroll
            for (int i = 0; i < 4; ++i) {
                const int gr = row0 + wm * 64 + mi * 16 + quad * 4 + i;
                out[(size_t)gr * H_ + gc] = acc[mi][ni][i] + bv;
            }
    }
}

// ---------------------------------------------------------------------------
// Flash attention v6, MFMA bf16.
//   R3/R4/R5 post-mortems: every pipeline attempt was defeated by an implicit
//   vmcnt drain caused by register-destination VMEM (mask loads) -- the
//   compiler waits on the YOUNGEST outstanding op before reading/copying the
//   register, draining the whole queue. v6 removes register VMEM from the
//   loop entirely:
//   * masks staged into LDS via global_load_lds, like K/V. Per tile per wave:
//     6 gl2lds (2 K + 2 V + 2 M) and NO other VMEM. FIFO ledger: at tile-t
//     top outstanding = stage(t+1)[6] -> s_waitcnt vmcnt(6) retires stage(t)
//     without draining. Depth-2 prefetch, 3 buffers.
//   * mask LDS chunk-swizzle via SOURCE address: jg = jp ^ (q&3) ^ ((q>>2)&3)
//     -> compute-side ds_read_b32 is <=2-way bank-conflicted (free).
//   * LDS 3*(8+8+8) = 72 KB -> 2 blocks/CU (R4 proved 2/CU sustains baseline).
//   * raw s_barrier + sched_barrier(0); setprio(1) around MFMA clusters.
//   * straight-line body, no lambdas/macros, static indices (R5 scratch fix).
// ---------------------------------------------------------------------------
__global__ __launch_bounds__(256, 2) void flash_mfma_kernel(
    const short* __restrict__ Qb, const short* __restrict__ Kb,
    const short* __restrict__ Vtb, const unsigned char* __restrict__ mask8,
    short* __restrict__ ctxb)
{
    const int bh = blockIdx.y;
    const int b  = bh >> 4;          // / NH_
    const int h  = bh & 15;          // % NH_
    const int s0 = blockIdx.x * 128;

    const int tdx  = threadIdx.x;
    const int wave = tdx >> 6;
    const int lane = tdx & 63;
    const int l15  = lane & 15;
    const int quad = lane >> 4;

    __shared__ __align__(16) short Ks [3 * 4096];           // [buf][key][d]
    __shared__ __align__(16) short Vts[3 * 4096];           // [buf][d][key]
    __shared__ __align__(16) unsigned char Ms[3 * 8192];    // [buf][q128][t64]

    // Q fragments: wave owns q rows [s0+wave*32, +32), 2 groups of 16
    const short* Qg = Qb + ((size_t)bh * S_ + s0 + wave * 32 + l15) * HD_;
    short8 qf00 = *(const short8*)(Qg + quad * 8);
    short8 qf01 = *(const short8*)(Qg + 32 + quad * 8);
    short8 qf10 = *(const short8*)(Qg + 16 * HD_ + quad * 8);
    short8 qf11 = *(const short8*)(Qg + 16 * HD_ + 32 + quad * 8);

    const short* Kbase  = Kb  + (size_t)bh * S_ * HD_;
    const short* Vtbase = Vtb + (size_t)bh * HD_ * S_;

    floatx4 o[2][4];
    float ls0 = 0.f, ls1 = 0.f;
#pragma unroll
    for (int g = 0; g < 2; ++g)
#pragma unroll
        for (int n0 = 0; n0 < 4; ++n0) o[g][n0] = (floatx4){0.f, 0.f, 0.f, 0.f};

    // K/V staging chunk geometry (per lane, loop-invariant)
    const int cb0 = wave * 64, cb1 = (4 + wave) * 64;
    const int c0 = cb0 + lane,  c1 = cb1 + lane;
    const int r0 = c0 >> 3, jg0 = ((c0 & 7) ^ (r0 & 7)) * 8;
    const int r1 = c1 >> 3, jg1 = ((c1 & 7) ^ (r1 & 7)) * 8;

    // M staging geometry: sub i: row q_r = wave*32 + i*16 + (lane>>2),
    // phys chunk jp = lane&3, global chunk jg = jp ^ (q&3) ^ ((q>>2)&3)
    const int mq0 = wave * 32 + (lane >> 2);
    const int mq1 = mq0 + 16;
    const int msw0 = (mq0 & 3) ^ ((mq0 >> 2) & 3);
    const int msw1 = (mq1 & 3) ^ ((mq1 >> 2) & 3);
    const unsigned char* msrc0 = mask8 + ((size_t)b * S_ + s0 + mq0) * S_ + ((lane & 3) ^ msw0) * 16;
    const unsigned char* msrc1 = mask8 + ((size_t)b * S_ + s0 + mq1) * S_ + ((lane & 3) ^ msw1) * 16;
    const int mdst0 = wave * 2048;           // + buf*8192; lane*16 auto
    const int mdst1 = wave * 2048 + 1024;

    // M compute-read geometry: q_local = wave*32 + g*16 + l15; the swizzle
    // term depends only on l15: sq = (l15&3) ^ (l15>>2)
    const int sq = (l15 & 3) ^ (l15 >> 2);
    const int mrd0 = (wave * 32 + l15) * 64 + quad * 4;          // group 0
    const int mrd1 = (wave * 32 + 16 + l15) * 64 + quad * 4;     // group 1

    // prologue: stage(0) -> buf0, stage(1) -> buf1 (FIFO blocks of 6)
    gl2lds16(Kbase  + (size_t)r0 * HD_ + jg0, &Ks[cb0 * 8]);
    gl2lds16(Kbase  + (size_t)r1 * HD_ + jg1, &Ks[cb1 * 8]);
    gl2lds16(Vtbase + (size_t)r0 * S_ + jg0,  &Vts[cb0 * 8]);
    gl2lds16(Vtbase + (size_t)r1 * S_ + jg1,  &Vts[cb1 * 8]);
    gl2lds16(msrc0, &Ms[mdst0]);
    gl2lds16(msrc1, &Ms[mdst1]);
    __builtin_amdgcn_sched_barrier(0);
    gl2lds16(Kbase  + (size_t)(64 + r0) * HD_ + jg0, &Ks[4096 + cb0 * 8]);
    gl2lds16(Kbase  + (size_t)(64 + r1) * HD_ + jg1, &Ks[4096 + cb1 * 8]);
    gl2lds16(Vtbase + (size_t)r0 * S_ + 64 + jg0,    &Vts[4096 + cb0 * 8]);
    gl2lds16(Vtbase + (size_t)r1 * S_ + 64 + jg1,    &Vts[4096 + cb1 * 8]);
    gl2lds16(msrc0 + 64, &Ms[8192 + mdst0]);
    gl2lds16(msrc1 + 64, &Ms[8192 + mdst1]);
    __builtin_amdgcn_sched_barrier(0);

    const floatx4 z4 = {0.f, 0.f, 0.f, 0.f};
    int bc = 0, bs = 2;   // compute / stage buffer indices

#pragma unroll 1
    for (int it = 0; it < 32; ++it) {
        // counted wait: stage(it) retired; stage(it+1) [6 ops] may remain
        if (it < 31) { asm volatile("s_waitcnt vmcnt(6)" ::: "memory"); }
        else         { asm volatile("s_waitcnt vmcnt(0)" ::: "memory"); }
        __builtin_amdgcn_s_barrier();
        __builtin_amdgcn_sched_barrier(0);

        // stage tile it+2 into buf bs (FIFO block of 6)
        if (it < 30) {
            const size_t tn = (size_t)(it + 2) * 64;
            gl2lds16(Kbase  + (tn + r0) * HD_ + jg0,      &Ks[bs * 4096 + cb0 * 8]);
            gl2lds16(Kbase  + (tn + r1) * HD_ + jg1,      &Ks[bs * 4096 + cb1 * 8]);
            gl2lds16(Vtbase + (size_t)r0 * S_ + tn + jg0, &Vts[bs * 4096 + cb0 * 8]);
            gl2lds16(Vtbase + (size_t)r1 * S_ + tn + jg1, &Vts[bs * 4096 + cb1 * 8]);
            gl2lds16(msrc0 + tn, &Ms[bs * 8192 + mdst0]);
            gl2lds16(msrc1 + tn, &Ms[bs * 8192 + mdst1]);
        }
        __builtin_amdgcn_sched_barrier(0);

        // ---- compute tile it from buf bc ----
        const int bo = bc * 4096;
        const int mo = bc * 8192;
        floatx4 sc[2][4];
        __builtin_amdgcn_s_setprio(1);
#pragma unroll
        for (int n0 = 0; n0 < 4; ++n0) {
            const int R = n0 * 16 + l15, xr = R & 7;
            const short8 kb0 = *(const short8*)&Ks[bo + R * 64 + ((quad ^ xr) * 8)];
            const short8 kb1 = *(const short8*)&Ks[bo + R * 64 + (((quad + 4) ^ xr) * 8)];
            sc[0][n0] = __builtin_amdgcn_mfma_f32_16x16x32_bf16(kb0, qf00, z4, 0, 0, 0);
            sc[0][n0] = __builtin_amdgcn_mfma_f32_16x16x32_bf16(kb1, qf01, sc[0][n0], 0, 0, 0);
            sc[1][n0] = __builtin_amdgcn_mfma_f32_16x16x32_bf16(kb0, qf10, z4, 0, 0, 0);
            sc[1][n0] = __builtin_amdgcn_mfma_f32_16x16x32_bf16(kb1, qf11, sc[1][n0], 0, 0, 0);
        }
        __builtin_amdgcn_s_setprio(0);

        unsigned uu[2][4][2];
#pragma unroll
        for (int g = 0; g < 2; ++g) {
            const int mrd = g ? mrd1 : mrd0;
#pragma unroll
            for (int n0 = 0; n0 < 4; ++n0) {
                const unsigned mw = *(const unsigned*)&Ms[mo + mrd + ((n0 ^ sq) << 4)];
                const floatx4 v = sc[g][n0];
                const unsigned q0 = __builtin_amdgcn_perm(0u, mw, 0x01010000u);
                const unsigned q1 = __builtin_amdgcn_perm(0u, mw, 0x03030202u);
                const unsigned u0 = pack_bf(__builtin_amdgcn_exp2f(v[0]),
                                            __builtin_amdgcn_exp2f(v[1])) & q0;
                const unsigned u1 = pack_bf(__builtin_amdgcn_exp2f(v[2]),
                                            __builtin_amdgcn_exp2f(v[3])) & q1;
                if (g == 0) ls0 += (bfl(u0) + bfh(u0)) + (bfl(u1) + bfh(u1));
                else        ls1 += (bfl(u0) + bfh(u0)) + (bfl(u1) + bfh(u1));
                uu[g][n0][0] = u0; uu[g][n0][1] = u1;
            }
        }
        short8 pa00 = pswz(uu[0][0][0], uu[0][0][1], uu[0][1][0], uu[0][1][1]);
        short8 pa01 = pswz(uu[0][2][0], uu[0][2][1], uu[0][3][0], uu[0][3][1]);
        short8 pa10 = pswz(uu[1][0][0], uu[1][0][1], uu[1][1][0], uu[1][1][1]);
        short8 pa11 = pswz(uu[1][2][0], uu[1][2][1], uu[1][3][0], uu[1][3][1]);

        __builtin_amdgcn_s_setprio(1);
#pragma unroll
        for (int n0 = 0; n0 < 4; ++n0) {
            const int R = n0 * 16 + l15, xr = R & 7;
            const short8 vb0 = *(const short8*)&Vts[bo + R * 64 + ((quad ^ xr) * 8)];
            const short8 vb1 = *(const short8*)&Vts[bo + R * 64 + (((quad + 4) ^ xr) * 8)];
            o[0][n0] = __builtin_amdgcn_mfma_f32_16x16x32_bf16(pa00, vb0, o[0][n0], 0, 0, 0);
            o[0][n0] = __builtin_amdgcn_mfma_f32_16x16x32_bf16(pa01, vb1, o[0][n0], 0, 0, 0);
            o[1][n0] = __builtin_amdgcn_mfma_f32_16x16x32_bf16(pa10, vb0, o[1][n0], 0, 0, 0);
            o[1][n0] = __builtin_amdgcn_mfma_f32_16x16x32_bf16(pa11, vb1, o[1][n0], 0, 0, 0);
        }
        __builtin_amdgcn_s_setprio(0);

        bc = (bc == 2) ? 0 : bc + 1;
        bs = (bs == 2) ? 0 : bs + 1;
    }

    // --- epilogue: l reduce over quads, normalize, store ---
#pragma unroll
    for (int g = 0; g < 2; ++g) {
        float lg = g ? ls1 : ls0;
        lg += __shfl_xor(lg, 16);
        lg += __shfl_xor(lg, 32);
        const float li = 1.f / lg;
#pragma unroll
        for (int i = 0; i < 4; ++i) {
            const float la = __shfl(li, quad * 4 + i);
            const int sA = s0 + wave * 32 + g * 16 + quad * 4 + i;
#pragma unroll
            for (int n0 = 0; n0 < 4; ++n0)
                ctxb[((size_t)sA * B_ + b) * H_ + h * HD_ + n0 * 16 + l15] =
                    f2bf(o[g][n0][i] * la);
        }
    }
}

// ---------------------------------------------------------------------------
extern "C" void kernel_launch(void* const* d_in, const int* in_sizes, int n_in,
                              void* d_out, int out_size, void* d_ws, size_t ws_size,
                              hipStream_t stream)
{
    const float* hidden = (const float*)d_in[0];
    const int*   mask   = (const int*)d_in[1];
    const float* Wqkv   = (const float*)d_in[2];
    const float* bqkv   = (const float*)d_in[3];
    const float* Wd     = (const float*)d_in[4];
    const float* bd     = (const float*)d_in[5];
    float* out = (float*)d_out;

    const size_t HE = (size_t)B_ * NH_ * S_ * HD_;   // 8388608
    short* hBF    = (short*)d_ws;
    short* WqkvBF = hBF + (size_t)S_ * B_ * H_;
    short* WdBF   = WqkvBF + (size_t)3 * H_ * H_;
    short* Qb     = WdBF + (size_t)H_ * H_;
    short* Kb     = Qb + HE;
    short* Vb     = Kb + HE;
    short* Vtb    = Vb + HE;
    short* ctxb   = Vtb + HE;
    // mask keep-bytes: B*S*S bytes == S*B*H*2 bytes -> alias hBF, which is
    // dead after gemm_qkv (mask_u8 launched after it, stream-ordered).
    unsigned char* mask8 = (unsigned char*)hBF;

    const int nh4 = (S_ * B_ * H_) / 4;   // 2097152
    const int nw4 = (3 * H_ * H_) / 4;    // 786432
    const int nd4 = (H_ * H_) / 4;        // 262144
    hipLaunchKernelGGL(cvt3_kernel, dim3((nh4 + nw4 + nd4) / 256), dim3(256), 0, stream,
                       hidden, hBF, nh4, Wqkv, WqkvBF, nw4, Wd, WdBF, nd4);

    hipLaunchKernelGGL(gemm_qkv_mfma, dim3((3 * H_) / 128, (S_ * B_) / 128), dim3(256), 0, stream,
                       hBF, WqkvBF, bqkv, Qb, Kb, Vb);
    hipLaunchKernelGGL(mask_u8_kernel, dim3((B_ * S_ * S_ / 4) / 256), dim3(256), 0, stream,
                       mask, (unsigned*)mask8);
    hipLaunchKernelGGL(vtrans_kernel, dim3(S_ / 64, B_ * NH_), dim3(256), 0, stream,
                       Vb, Vtb);
    hipLaunchKernelGGL(flash_mfma_kernel, dim3(S_ / 128, B_ * NH_), dim3(256), 0, stream,
                       Qb, Kb, Vtb, mask8, ctxb);
    hipLaunchKernelGGL(gemm_dense_mfma, dim3(H_ / 128, (S_ * B_) / 128), dim3(256), 0, stream,
                       ctxb, WdBF, bd, out);
}

// Round 7
// 360.110 us; speedup vs baseline: 1.2216x; 1.0097x over previous
//
#include <hip/hip_runtime.h>
#include <hip/hip_bf16.h>
#include <math.h>

// S,B,H,NH = 2048,4,1024,16; HD=64
constexpr int S_ = 2048, B_ = 4, H_ = 1024, NH_ = 16, HD_ = 64;

typedef __attribute__((ext_vector_type(8))) short short8;   // 8 bf16 (4 VGPRs)
typedef __attribute__((ext_vector_type(4))) short short4v;  // 4 bf16
typedef __attribute__((ext_vector_type(4))) float floatx4;  // MFMA C/D
typedef __attribute__((ext_vector_type(2))) unsigned uint2v;

static __device__ __forceinline__ short f2bf(float f) {
    union { float f; unsigned u; } v; v.f = f;
    unsigned r = v.u + 0x7FFFu + ((v.u >> 16) & 1u);  // RNE
    return (short)(r >> 16);
}

// pack two f32 -> one u32 of two bf16 (truncation), via v_perm_b32
static __device__ __forceinline__ unsigned pack_bf(float p0, float p1) {
    return __builtin_amdgcn_perm(__float_as_uint(p1), __float_as_uint(p0), 0x07060302u);
}

// async global->LDS, 16B per lane; LDS dest = wave-uniform base + lane*16
static __device__ __forceinline__ void gl2lds16(const void* g, void* l) {
    __builtin_amdgcn_global_load_lds(
        (const __attribute__((address_space(1))) void*)g,
        (__attribute__((address_space(3))) void*)l, 16, 0, 0);
}

// P-fragment redistribution (in-register, replaces Ps LDS round-trip).
static __device__ __forceinline__ short8 pswz(unsigned a0, unsigned a1,
                                              unsigned b0, unsigned b1) {
    uint2v r0 = __builtin_amdgcn_permlane32_swap(a0, b0, false, false);
    uint2v s0 = __builtin_amdgcn_permlane16_swap(r0.x, r0.y, false, false);
    uint2v r1 = __builtin_amdgcn_permlane32_swap(a1, b1, false, false);
    uint2v s1 = __builtin_amdgcn_permlane16_swap(r1.x, r1.y, false, false);
    union { unsigned u[4]; short8 s; } o;
    o.u[0] = s0.x;  // W0: t = dq*8 + {0,1}
    o.u[1] = s1.x;  // W1: t = dq*8 + {2,3}
    o.u[2] = s0.y;  // W2: t = dq*8 + {4,5}
    o.u[3] = s1.y;  // W3: t = dq*8 + {6,7}
    return o.s;
}

// ---------------------------------------------------------------------------
// fused fp32 -> bf16 convert for hidden / Wqkv / Wd
// ---------------------------------------------------------------------------
__global__ __launch_bounds__(256) void cvt3_kernel(
    const float* __restrict__ a, short* __restrict__ oa, int na,
    const float* __restrict__ b, short* __restrict__ ob, int nb,
    const float* __restrict__ c, short* __restrict__ oc, int nc)
{
    const int idx = blockIdx.x * 256 + threadIdx.x;
    const float* src; short* dst; int i;
    if (idx < na)            { src = a; dst = oa; i = idx; }
    else if (idx < na + nb)  { src = b; dst = ob; i = idx - na; }
    else                     { src = c; dst = oc; i = idx - na - nb; }
    const float4 v = ((const float4*)src)[i];
    short4v o = { (short)f2bf(v.x), (short)f2bf(v.y), (short)f2bf(v.z), (short)f2bf(v.w) };
    ((short4v*)dst)[i] = o;
}

// ---------------------------------------------------------------------------
// mask int32 -> keep-bytes (0xFF = keep, 0x00 = masked). 4 ints -> 1 dword.
// ---------------------------------------------------------------------------
__global__ __launch_bounds__(256) void mask_u8_kernel(
    const int* __restrict__ m, unsigned* __restrict__ mb)
{
    const int i = blockIdx.x * 256 + threadIdx.x;
    const int4 v = ((const int4*)m)[i];
    unsigned r = (v.x ? 0u : 0xFFu)      | (v.y ? 0u : 0xFF00u) |
                 (v.z ? 0u : 0xFF0000u)  | (v.w ? 0u : 0xFF000000u);
    mb[i] = r;
}

// ---------------------------------------------------------------------------
// QKV GEMM v2: BK=32, 3 LDS buffers, depth-2 counted-vmcnt pipeline (v6
// flash recipe). All loop VMEM is gl2lds (FIFO, no register dests). Per
// K-step per wave: 4 gl2lds -> vmcnt(4) at body top retires stage(k),
// stage(k+1)+stage(k+2) stay in flight. Latin-square chunk swizzle
// swz(r)=((r&3)+((r>>2)&3))&3 -> 2-way-free b128 frag reads. 48 KB LDS ->
// 3 blocks/CU. Epilogue unchanged: Qb/Kb/Vb [bh][s][d], Q pre-scaled by
// 0.125*log2(e).
// ---------------------------------------------------------------------------
__global__ __launch_bounds__(256, 3) void gemm_qkv_mfma(
    const short* __restrict__ A, const short* __restrict__ Bw,
    const float* __restrict__ bias,
    short* __restrict__ Qb, short* __restrict__ Kb, short* __restrict__ Vb)
{
    constexpr int K = H_;  // 1024
    __shared__ __align__(16) short As[3 * 4096];
    __shared__ __align__(16) short Bs[3 * 4096];

    const int t = threadIdx.x;
    const int wave = t >> 6, lane = t & 63;
    const int l15 = lane & 15, quad = lane >> 4;
    const int wm = wave & 1, wn = wave >> 1;
    const int row0 = blockIdx.y * 128;
    const int col0 = blockIdx.x * 128;

    floatx4 acc[4][4];
#pragma unroll
    for (int mi = 0; mi < 4; ++mi)
#pragma unroll
        for (int ni = 0; ni < 4; ++ni)
            acc[mi][ni] = (floatx4){0.f, 0.f, 0.f, 0.f};

    // staging geometry: 512 chunks(16B) per 128x32 tile; wave stages 128.
    const int c0 = wave * 128 + lane, c1 = c0 + 64;
    const int r0 = c0 >> 2, jg0 = (((c0 & 3) ^ (((r0 & 3) + ((r0 >> 2) & 3)) & 3))) * 8;
    const int r1 = c1 >> 2, jg1 = (((c1 & 3) ^ (((r1 & 3) + ((r1 >> 2) & 3)) & 3))) * 8;
    const int db0 = (wave * 128) * 8;      // uniform dst base (elems) + buf*4096
    const int db1 = db0 + 64 * 8;

    const short* Ar0 = A  + (size_t)(row0 + r0) * K + jg0;
    const short* Ar1 = A  + (size_t)(row0 + r1) * K + jg1;
    const short* Br0 = Bw + (size_t)(col0 + r0) * K + jg0;
    const short* Br1 = Bw + (size_t)(col0 + r1) * K + jg1;

    // prologue: stage(0) -> buf0, stage(1) -> buf1 (FIFO blocks of 4)
    gl2lds16(Ar0, &As[db0]); gl2lds16(Ar1, &As[db1]);
    gl2lds16(Br0, &Bs[db0]); gl2lds16(Br1, &Bs[db1]);
    __builtin_amdgcn_sched_barrier(0);
    gl2lds16(Ar0 + 32, &As[4096 + db0]); gl2lds16(Ar1 + 32, &As[4096 + db1]);
    gl2lds16(Br0 + 32, &Bs[4096 + db0]); gl2lds16(Br1 + 32, &Bs[4096 + db1]);
    __builtin_amdgcn_sched_barrier(0);

    int bc = 0, bs = 2;
#pragma unroll 1
    for (int it = 0; it < 32; ++it) {
        if (it < 31) { asm volatile("s_waitcnt vmcnt(4)" ::: "memory"); }
        else         { asm volatile("s_waitcnt vmcnt(0)" ::: "memory"); }
        __builtin_amdgcn_s_barrier();
        __builtin_amdgcn_sched_barrier(0);

        if (it < 30) {
            const int ko = (it + 2) * 32;
            gl2lds16(Ar0 + ko, &As[bs * 4096 + db0]);
            gl2lds16(Ar1 + ko, &As[bs * 4096 + db1]);
            gl2lds16(Br0 + ko, &Bs[bs * 4096 + db0]);
            gl2lds16(Br1 + ko, &Bs[bs * 4096 + db1]);
        }
        __builtin_amdgcn_sched_barrier(0);

        const int bo = bc * 4096;
        short8 af[4], bfr[4];
#pragma unroll
        for (int mi = 0; mi < 4; ++mi) {
            const int R = wm * 64 + mi * 16 + l15;
            const int sel = quad ^ (((R & 3) + ((R >> 2) & 3)) & 3);
            af[mi] = *(const short8*)&As[bo + R * 32 + sel * 8];
        }
#pragma unroll
        for (int ni = 0; ni < 4; ++ni) {
            const int R = wn * 64 + ni * 16 + l15;
            const int sel = quad ^ (((R & 3) + ((R >> 2) & 3)) & 3);
            bfr[ni] = *(const short8*)&Bs[bo + R * 32 + sel * 8];
        }
        __builtin_amdgcn_s_setprio(1);
#pragma unroll
        for (int mi = 0; mi < 4; ++mi)
#pragma unroll
            for (int ni = 0; ni < 4; ++ni)
                acc[mi][ni] = __builtin_amdgcn_mfma_f32_16x16x32_bf16(
                    af[mi], bfr[ni], acc[mi][ni], 0, 0, 0);
        __builtin_amdgcn_s_setprio(0);

        bc = (bc == 2) ? 0 : bc + 1;
        bs = (bs == 2) ? 0 : bs + 1;
    }

#pragma unroll
    for (int ni = 0; ni < 4; ++ni) {
        const int gc = col0 + wn * 64 + ni * 16 + l15;
        const float bv = bias[gc];
        const int hh = gc / 192;
        const int rem = gc - hh * 192;
        const int which = rem >> 6, d = rem & 63;
#pragma unroll
        for (int mi = 0; mi < 4; ++mi)
#pragma unroll
            for (int i = 0; i < 4; ++i) {
                const int gr = row0 + wm * 64 + mi * 16 + quad * 4 + i;
                const int s = gr >> 2, bb = gr & 3;      // row = s*B + b
                float fv = acc[mi][ni][i] + bv;
                const size_t ho = (size_t)(bb * NH_ + hh);
                // 0.125 * log2(e): scores arrive pre-multiplied for exp2
                if (which == 0)      Qb[(ho * S_ + s) * HD_ + d] = f2bf(fv * 0.1803368801111204f);
                else if (which == 1) Kb[(ho * S_ + s) * HD_ + d] = f2bf(fv);
                else                 Vb[(ho * S_ + s) * HD_ + d] = f2bf(fv);
            }
    }
}

// ---------------------------------------------------------------------------
// V transpose: Vb [bh][s][d] -> Vtb [bh][d][s], 64x64 tiles via swizzled LDS.
// ---------------------------------------------------------------------------
__global__ __launch_bounds__(256) void vtrans_kernel(
    const short* __restrict__ Vb, short* __restrict__ Vtb)
{
    const int bh = blockIdx.y;
    const int s0 = blockIdx.x * 64;
    __shared__ __align__(16) short T[64 * 64];
    const int t = threadIdx.x;

#pragma unroll
    for (int it = 0; it < 2; ++it) {
        const int c = t + it * 256;
        const int r = c >> 3, jp = c & 7;
        const int jg = jp ^ ((r >> 3) & 7);
        *(short8*)&T[r * 64 + jp * 8] =
            *(const short8*)(Vb + ((size_t)bh * S_ + s0 + r) * HD_ + jg * 8);
    }
    __syncthreads();

#pragma unroll
    for (int it = 0; it < 2; ++it) {
        const int c = t + it * 256;
        const int d = c >> 3, sg = (c & 7) * 8;
        short8 v;
#pragma unroll
        for (int k = 0; k < 8; ++k) {
            const int r = sg + k;
            v[k] = T[r * 64 + (((d >> 3) ^ ((r >> 3) & 7)) * 8) + (d & 7)];
        }
        *(short8*)(Vtb + ((size_t)bh * HD_ + d) * S_ + s0 + sg) = v;
    }
}

// ---------------------------------------------------------------------------
// Dense GEMM v2: same BK=32 depth-2 counted-vmcnt pipeline as gemm_qkv.
// out = ctxb @ Wd^T + bd (fp32 out)
// ---------------------------------------------------------------------------
__global__ __launch_bounds__(256, 3) void gemm_dense_mfma(
    const short* __restrict__ A, const short* __restrict__ Bw,
    const float* __restrict__ bias, float* __restrict__ out)
{
    constexpr int K = H_;  // 1024
    __shared__ __align__(16) short As[3 * 4096];
    __shared__ __align__(16) short Bs[3 * 4096];

    const int t = threadIdx.x;
    const int wave = t >> 6, lane = t & 63;
    const int l15 = lane & 15, quad = lane >> 4;
    const int wm = wave & 1, wn = wave >> 1;
    const int row0 = blockIdx.y * 128;
    const int col0 = blockIdx.x * 128;

    floatx4 acc[4][4];
#pragma unroll
    for (int mi = 0; mi < 4; ++mi)
#pragma unroll
        for (int ni = 0; ni < 4; ++ni)
            acc[mi][ni] = (floatx4){0.f, 0.f, 0.f, 0.f};

    const int c0 = wave * 128 + lane, c1 = c0 + 64;
    const int r0 = c0 >> 2, jg0 = (((c0 & 3) ^ (((r0 & 3) + ((r0 >> 2) & 3)) & 3))) * 8;
    const int r1 = c1 >> 2, jg1 = (((c1 & 3) ^ (((r1 & 3) + ((r1 >> 2) & 3)) & 3))) * 8;
    const int db0 = (wave * 128) * 8;
    const int db1 = db0 + 64 * 8;

    const short* Ar0 = A  + (size_t)(row0 + r0) * K + jg0;
    const short* Ar1 = A  + (size_t)(row0 + r1) * K + jg1;
    const short* Br0 = Bw + (size_t)(col0 + r0) * K + jg0;
    const short* Br1 = Bw + (size_t)(col0 + r1) * K + jg1;

    gl2lds16(Ar0, &As[db0]); gl2lds16(Ar1, &As[db1]);
    gl2lds16(Br0, &Bs[db0]); gl2lds16(Br1, &Bs[db1]);
    __builtin_amdgcn_sched_barrier(0);
    gl2lds16(Ar0 + 32, &As[4096 + db0]); gl2lds16(Ar1 + 32, &As[4096 + db1]);
    gl2lds16(Br0 + 32, &Bs[4096 + db0]); gl2lds16(Br1 + 32, &Bs[4096 + db1]);
    __builtin_amdgcn_sched_barrier(0);

    int bc = 0, bs = 2;
#pragma unroll 1
    for (int it = 0; it < 32; ++it) {
        if (it < 31) { asm volatile("s_waitcnt vmcnt(4)" ::: "memory"); }
        else         { asm volatile("s_waitcnt vmcnt(0)" ::: "memory"); }
        __builtin_amdgcn_s_barrier();
        __builtin_amdgcn_sched_barrier(0);

        if (it < 30) {
            const int ko = (it + 2) * 32;
            gl2lds16(Ar0 + ko, &As[bs * 4096 + db0]);
            gl2lds16(Ar1 + ko, &As[bs * 4096 + db1]);
            gl2lds16(Br0 + ko, &Bs[bs * 4096 + db0]);
            gl2lds16(Br1 + ko, &Bs[bs * 4096 + db1]);
        }
        __builtin_amdgcn_sched_barrier(0);

        const int bo = bc * 4096;
        short8 af[4], bfr[4];
#pragma unroll
        for (int mi = 0; mi < 4; ++mi) {
            const int R = wm * 64 + mi * 16 + l15;
            const int sel = quad ^ (((R & 3) + ((R >> 2) & 3)) & 3);
            af[mi] = *(const short8*)&As[bo + R * 32 + sel * 8];
        }
#pragma unroll
        for (int ni = 0; ni < 4; ++ni) {
            const int R = wn * 64 + ni * 16 + l15;
            const int sel = quad ^ (((R & 3) + ((R >> 2) & 3)) & 3);
            bfr[ni] = *(const short8*)&Bs[bo + R * 32 + sel * 8];
        }
        __builtin_amdgcn_s_setprio(1);
#pragma unroll
        for (int mi = 0; mi < 4; ++mi)
#pragma unroll
            for (int ni = 0; ni < 4; ++ni)
                acc[mi][ni] = __builtin_amdgcn_mfma_f32_16x16x32_bf16(
                    af[mi], bfr[ni], acc[mi][ni], 0, 0, 0);
        __builtin_amdgcn_s_setprio(0);

        bc = (bc == 2) ? 0 : bc + 1;
        bs = (bs == 2) ? 0 : bs + 1;
    }

#pragma unroll
    for (int ni = 0; ni < 4; ++ni) {
        const int gc = col0 + wn * 64 + ni * 16 + l15;
        const float bv = bias[gc];
#pragma unroll
        for (int mi = 0; mi < 4; ++mi)
#pragma unroll
            for (int i = 0; i < 4; ++i) {
                const int gr = row0 + wm * 64 + mi * 16 + quad * 4 + i;
                out[(size_t)gr * H_ + gc] = acc[mi][ni][i] + bv;
            }
    }
}

// ---------------------------------------------------------------------------
// Flash attention v7, MFMA bf16.
//   v6 (counted-vmcnt all-LDS pipeline) verified: 165 -> 120 us, no spill.
//   R6 counters: VALUBusy 50 vs MfmaUtil 24 -> VALU-throttled. v7 removes
//   the biggest VALU block: the l-accumulation chain (bfl/bfh extract + adds,
//   ~56 VALU/tile) is replaced by MFMA with an all-ones B operand:
//     lacc[g] += mfma(pa_g0, ones) + mfma(pa_g1, ones)
//   D[m][n] = sum_t P[q][t]*1 for every column n, and the C/D layout puts
//   lacc[g][i] in exactly the (quad,i) lane-position the store loop uses ->
//   the epilogue cross-lane shuffles disappear too. 4 extra MFMA/tile
//   (~20 cyc) for ~112 cyc VALU removed. Pipeline/staging identical to v6.
// ---------------------------------------------------------------------------
__global__ __launch_bounds__(256, 2) void flash_mfma_kernel(
    const short* __restrict__ Qb, const short* __restrict__ Kb,
    const short* __restrict__ Vtb, const unsigned char* __restrict__ mask8,
    short* __restrict__ ctxb)
{
    const int bh = blockIdx.y;
    const int b  = bh >> 4;          // / NH_
    const int h  = bh & 15;          // % NH_
    const int s0 = blockIdx.x * 128;

    const int tdx  = threadIdx.x;
    const int wave = tdx >> 6;
    const int lane = tdx & 63;
    const int l15  = lane & 15;
    const int quad = lane >> 4;

    __shared__ __align__(16) short Ks [3 * 4096];           // [buf][key][d]
    __shared__ __align__(16) short Vts[3 * 4096];           // [buf][d][key]
    __shared__ __align__(16) unsigned char Ms[3 * 8192];    // [buf][q128][t64]

    // Q fragments: wave owns q rows [s0+wave*32, +32), 2 groups of 16
    const short* Qg = Qb + ((size_t)bh * S_ + s0 + wave * 32 + l15) * HD_;
    short8 qf00 = *(const short8*)(Qg + quad * 8);
    short8 qf01 = *(const short8*)(Qg + 32 + quad * 8);
    short8 qf10 = *(const short8*)(Qg + 16 * HD_ + quad * 8);
    short8 qf11 = *(const short8*)(Qg + 16 * HD_ + 32 + quad * 8);

    const short* Kbase  = Kb  + (size_t)bh * S_ * HD_;
    const short* Vtbase = Vtb + (size_t)bh * HD_ * S_;

    floatx4 o[2][4];
    floatx4 lacc[2];
#pragma unroll
    for (int g = 0; g < 2; ++g) {
        lacc[g] = (floatx4){0.f, 0.f, 0.f, 0.f};
#pragma unroll
        for (int n0 = 0; n0 < 4; ++n0) o[g][n0] = (floatx4){0.f, 0.f, 0.f, 0.f};
    }
    const short8 ones8 = {(short)0x3F80, (short)0x3F80, (short)0x3F80, (short)0x3F80,
                          (short)0x3F80, (short)0x3F80, (short)0x3F80, (short)0x3F80};

    // K/V staging chunk geometry (per lane, loop-invariant)
    const int cb0 = wave * 64, cb1 = (4 + wave) * 64;
    const int c0 = cb0 + lane,  c1 = cb1 + lane;
    const int r0 = c0 >> 3, jg0 = ((c0 & 7) ^ (r0 & 7)) * 8;
    const int r1 = c1 >> 3, jg1 = ((c1 & 7) ^ (r1 & 7)) * 8;

    // M staging geometry: sub i: row q_r = wave*32 + i*16 + (lane>>2),
    // phys chunk jp = lane&3, global chunk jg = jp ^ (q&3) ^ ((q>>2)&3)
    const int mq0 = wave * 32 + (lane >> 2);
    const int mq1 = mq0 + 16;
    const int msw0 = (mq0 & 3) ^ ((mq0 >> 2) & 3);
    const int msw1 = (mq1 & 3) ^ ((mq1 >> 2) & 3);
    const unsigned char* msrc0 = mask8 + ((size_t)b * S_ + s0 + mq0) * S_ + ((lane & 3) ^ msw0) * 16;
    const unsigned char* msrc1 = mask8 + ((size_t)b * S_ + s0 + mq1) * S_ + ((lane & 3) ^ msw1) * 16;
    const int mdst0 = wave * 2048;           // + buf*8192; lane*16 auto
    const int mdst1 = wave * 2048 + 1024;

    // M compute-read geometry: q_local = wave*32 + g*16 + l15; the swizzle
    // term depends only on l15: sq = (l15&3) ^ (l15>>2)
    const int sq = (l15 & 3) ^ (l15 >> 2);
    const int mrd0 = (wave * 32 + l15) * 64 + quad * 4;          // group 0
    const int mrd1 = (wave * 32 + 16 + l15) * 64 + quad * 4;     // group 1

    // prologue: stage(0) -> buf0, stage(1) -> buf1 (FIFO blocks of 6)
    gl2lds16(Kbase  + (size_t)r0 * HD_ + jg0, &Ks[cb0 * 8]);
    gl2lds16(Kbase  + (size_t)r1 * HD_ + jg1, &Ks[cb1 * 8]);
    gl2lds16(Vtbase + (size_t)r0 * S_ + jg0,  &Vts[cb0 * 8]);
    gl2lds16(Vtbase + (size_t)r1 * S_ + jg1,  &Vts[cb1 * 8]);
    gl2lds16(msrc0, &Ms[mdst0]);
    gl2lds16(msrc1, &Ms[mdst1]);
    __builtin_amdgcn_sched_barrier(0);
    gl2lds16(Kbase  + (size_t)(64 + r0) * HD_ + jg0, &Ks[4096 + cb0 * 8]);
    gl2lds16(Kbase  + (size_t)(64 + r1) * HD_ + jg1, &Ks[4096 + cb1 * 8]);
    gl2lds16(Vtbase + (size_t)r0 * S_ + 64 + jg0,    &Vts[4096 + cb0 * 8]);
    gl2lds16(Vtbase + (size_t)r1 * S_ + 64 + jg1,    &Vts[4096 + cb1 * 8]);
    gl2lds16(msrc0 + 64, &Ms[8192 + mdst0]);
    gl2lds16(msrc1 + 64, &Ms[8192 + mdst1]);
    __builtin_amdgcn_sched_barrier(0);

    const floatx4 z4 = {0.f, 0.f, 0.f, 0.f};
    int bc = 0, bs = 2;   // compute / stage buffer indices

#pragma unroll 1
    for (int it = 0; it < 32; ++it) {
        // counted wait: stage(it) retired; stage(it+1) [6 ops] may remain
        if (it < 31) { asm volatile("s_waitcnt vmcnt(6)" ::: "memory"); }
        else         { asm volatile("s_waitcnt vmcnt(0)" ::: "memory"); }
        __builtin_amdgcn_s_barrier();
        __builtin_amdgcn_sched_barrier(0);

        // stage tile it+2 into buf bs (FIFO block of 6)
        if (it < 30) {
            const size_t tn = (size_t)(it + 2) * 64;
            gl2lds16(Kbase  + (tn + r0) * HD_ + jg0,      &Ks[bs * 4096 + cb0 * 8]);
            gl2lds16(Kbase  + (tn + r1) * HD_ + jg1,      &Ks[bs * 4096 + cb1 * 8]);
            gl2lds16(Vtbase + (size_t)r0 * S_ + tn + jg0, &Vts[bs * 4096 + cb0 * 8]);
            gl2lds16(Vtbase + (size_t)r1 * S_ + tn + jg1, &Vts[bs * 4096 + cb1 * 8]);
            gl2lds16(msrc0 + tn, &Ms[bs * 8192 + mdst0]);
            gl2lds16(msrc1 + tn, &Ms[bs * 8192 + mdst1]);
        }
        __builtin_amdgcn_sched_barrier(0);

        // ---- compute tile it from buf bc ----
        const int bo = bc * 4096;
        const int mo = bc * 8192;
        floatx4 sc[2][4];
        __builtin_amdgcn_s_setprio(1);
#pragma unroll
        for (int n0 = 0; n0 < 4; ++n0) {
            const int R = n0 * 16 + l15, xr = R & 7;
            const short8 kb0 = *(const short8*)&Ks[bo + R * 64 + ((quad ^ xr) * 8)];
            const short8 kb1 = *(const short8*)&Ks[bo + R * 64 + (((quad + 4) ^ xr) * 8)];
            sc[0][n0] = __builtin_amdgcn_mfma_f32_16x16x32_bf16(kb0, qf00, z4, 0, 0, 0);
            sc[0][n0] = __builtin_amdgcn_mfma_f32_16x16x32_bf16(kb1, qf01, sc[0][n0], 0, 0, 0);
            sc[1][n0] = __builtin_amdgcn_mfma_f32_16x16x32_bf16(kb0, qf10, z4, 0, 0, 0);
            sc[1][n0] = __builtin_amdgcn_mfma_f32_16x16x32_bf16(kb1, qf11, sc[1][n0], 0, 0, 0);
        }
        __builtin_amdgcn_s_setprio(0);

        unsigned uu[2][4][2];
#pragma unroll
        for (int g = 0; g < 2; ++g) {
            const int mrd = g ? mrd1 : mrd0;
#pragma unroll
            for (int n0 = 0; n0 < 4; ++n0) {
                const unsigned mw = *(const unsigned*)&Ms[mo + mrd + ((n0 ^ sq) << 4)];
                const floatx4 v = sc[g][n0];
                const unsigned q0 = __builtin_amdgcn_perm(0u, mw, 0x01010000u);
                const unsigned q1 = __builtin_amdgcn_perm(0u, mw, 0x03030202u);
                const unsigned u0 = pack_bf(__builtin_amdgcn_exp2f(v[0]),
                                            __builtin_amdgcn_exp2f(v[1])) & q0;
                const unsigned u1 = pack_bf(__builtin_amdgcn_exp2f(v[2]),
                                            __builtin_amdgcn_exp2f(v[3])) & q1;
                uu[g][n0][0] = u0; uu[g][n0][1] = u1;
            }
        }
        short8 pa00 = pswz(uu[0][0][0], uu[0][0][1], uu[0][1][0], uu[0][1][1]);
        short8 pa01 = pswz(uu[0][2][0], uu[0][2][1], uu[0][3][0], uu[0][3][1]);
        short8 pa10 = pswz(uu[1][0][0], uu[1][0][1], uu[1][1][0], uu[1][1][1]);
        short8 pa11 = pswz(uu[1][2][0], uu[1][2][1], uu[1][3][0], uu[1][3][1]);

        __builtin_amdgcn_s_setprio(1);
        // l accumulation via all-ones B operand (replaces the VALU chain)
        lacc[0] = __builtin_amdgcn_mfma_f32_16x16x32_bf16(pa00, ones8, lacc[0], 0, 0, 0);
        lacc[0] = __builtin_amdgcn_mfma_f32_16x16x32_bf16(pa01, ones8, lacc[0], 0, 0, 0);
        lacc[1] = __builtin_amdgcn_mfma_f32_16x16x32_bf16(pa10, ones8, lacc[1], 0, 0, 0);
        lacc[1] = __builtin_amdgcn_mfma_f32_16x16x32_bf16(pa11, ones8, lacc[1], 0, 0, 0);
#pragma unroll
        for (int n0 = 0; n0 < 4; ++n0) {
            const int R = n0 * 16 + l15, xr = R & 7;
            const short8 vb0 = *(const short8*)&Vts[bo + R * 64 + ((quad ^ xr) * 8)];
            const short8 vb1 = *(const short8*)&Vts[bo + R * 64 + (((quad + 4) ^ xr) * 8)];
            o[0][n0] = __builtin_amdgcn_mfma_f32_16x16x32_bf16(pa00, vb0, o[0][n0], 0, 0, 0);
            o[0][n0] = __builtin_amdgcn_mfma_f32_16x16x32_bf16(pa01, vb1, o[0][n0], 0, 0, 0);
            o[1][n0] = __builtin_amdgcn_mfma_f32_16x16x32_bf16(pa10, vb0, o[1][n0], 0, 0, 0);
            o[1][n0] = __builtin_amdgcn_mfma_f32_16x16x32_bf16(pa11, vb1, o[1][n0], 0, 0, 0);
        }
        __builtin_amdgcn_s_setprio(0);

        bc = (bc == 2) ? 0 : bc + 1;
        bs = (bs == 2) ? 0 : bs + 1;
    }

    // --- epilogue: lacc[g][i] = l[q = g*16 + quad*4 + i] in-lane; no shuffles
#pragma unroll
    for (int g = 0; g < 2; ++g) {
#pragma unroll
        for (int i = 0; i < 4; ++i) {
            const float la = 1.f / lacc[g][i];
            const int sA = s0 + wave * 32 + g * 16 + quad * 4 + i;
#pragma unroll
            for (int n0 = 0; n0 < 4; ++n0)
                ctxb[((size_t)sA * B_ + b) * H_ + h * HD_ + n0 * 16 + l15] =
                    f2bf(o[g][n0][i] * la);
        }
    }
}

// ---------------------------------------------------------------------------
extern "C" void kernel_launch(void* const* d_in, const int* in_sizes, int n_in,
                              void* d_out, int out_size, void* d_ws, size_t ws_size,
                              hipStream_t stream)
{
    const float* hidden = (const float*)d_in[0];
    const int*   mask   = (const int*)d_in[1];
    const float* Wqkv   = (const float*)d_in[2];
    const float* bqkv   = (const float*)d_in[3];
    const float* Wd     = (const float*)d_in[4];
    const float* bd     = (const float*)d_in[5];
    float* out = (float*)d_out;

    const size_t HE = (size_t)B_ * NH_ * S_ * HD_;   // 8388608
    short* hBF    = (short*)d_ws;
    short* WqkvBF = hBF + (size_t)S_ * B_ * H_;
    short* WdBF   = WqkvBF + (size_t)3 * H_ * H_;
    short* Qb     = WdBF + (size_t)H_ * H_;
    short* Kb     = Qb + HE;
    short* Vb     = Kb + HE;
    short* Vtb    = Vb + HE;
    short* ctxb   = Vtb + HE;
    // mask keep-bytes: B*S*S bytes == S*B*H*2 bytes -> alias hBF, which is
    // dead after gemm_qkv (mask_u8 launched after it, stream-ordered).
    unsigned char* mask8 = (unsigned char*)hBF;

    const int nh4 = (S_ * B_ * H_) / 4;   // 2097152
    const int nw4 = (3 * H_ * H_) / 4;    // 786432
    const int nd4 = (H_ * H_) / 4;        // 262144
    hipLaunchKernelGGL(cvt3_kernel, dim3((nh4 + nw4 + nd4) / 256), dim3(256), 0, stream,
                       hidden, hBF, nh4, Wqkv, WqkvBF, nw4, Wd, WdBF, nd4);

    hipLaunchKernelGGL(gemm_qkv_mfma, dim3((3 * H_) / 128, (S_ * B_) / 128), dim3(256), 0, stream,
                       hBF, WqkvBF, bqkv, Qb, Kb, Vb);
    hipLaunchKernelGGL(mask_u8_kernel, dim3((B_ * S_ * S_ / 4) / 256), dim3(256), 0, stream,
                       mask, (unsigned*)mask8);
    hipLaunchKernelGGL(vtrans_kernel, dim3(S_ / 64, B_ * NH_), dim3(256), 0, stream,
                       Vb, Vtb);
    hipLaunchKernelGGL(flash_mfma_kernel, dim3(S_ / 128, B_ * NH_), dim3(256), 0, stream,
                       Qb, Kb, Vtb, mask8, ctxb);
    hipLaunchKernelGGL(gemm_dense_mfma, dim3(H_ / 128, (S_ * B_) / 128), dim3(256), 0, stream,
                       ctxb, WdBF, bd, out);
}